// Round 6
// baseline (140.621 us; speedup 1.0000x reference)
//
#include <hip/hip_runtime.h>
#include <hip/hip_bf16.h>

#define B_ROWS 32768

typedef unsigned short u16;
typedef unsigned int u32;
typedef float f32x4 __attribute__((ext_vector_type(4)));
typedef __bf16 bf16x8 __attribute__((ext_vector_type(8)));

__device__ __forceinline__ u16 f2bf(float f){
    union { float f; u32 u; } v; v.f = f;
    return (u16)((v.u + 0x7FFFu + ((v.u >> 16) & 1u)) >> 16);
}
__device__ __forceinline__ float bf2f(u16 h){
    union { u32 u; float f; } v; v.u = ((u32)h) << 16; return v.f;
}
// v_cvt_pk_bf16_f32: dst.lo = bf16(lo), dst.hi = bf16(hi), RNE
__device__ __forceinline__ u32 cvtpk(float lo, float hi){
    u32 r;
    asm("v_cvt_pk_bf16_f32 %0, %1, %2" : "=v"(r) : "v"(lo), "v"(hi));
    return r;
}
__device__ __forceinline__ void async_cp16(void* lds_dst, const void* g_src){
    __builtin_amdgcn_global_load_lds(
        (const __attribute__((address_space(1))) unsigned int*)g_src,
        (__attribute__((address_space(3))) unsigned int*)lds_dst, 16, 0, 0);
}

// ---------------- weight cast/transpose into staging-friendly images ----------
// pimg : [3][12][8192]  XOR-swizzled proj-B LDS image
// w1img: [8][12 chunks][q:4][col:128][8]  (chunk ph covers k = ph*32 + q*8 + el)
// w2img: [8][4 chunks][q:4][col:128][8]
// prwT : [64][128] plain [o][k]
// gwimg: [16][384] zero-padded gate weights, [e][k]
__global__ void cast_weights_kernel(const float* __restrict__ proj_w,
                                    const float* __restrict__ exp_w1,
                                    const float* __restrict__ exp_w2,
                                    const float* __restrict__ pre_w,
                                    const float* __restrict__ gate_w,
                                    u16* __restrict__ pimg, u16* __restrict__ w1img,
                                    u16* __restrict__ w2img, u16* __restrict__ prwT,
                                    u16* __restrict__ gwimg){
    int i = blockIdx.x * 256 + threadIdx.x;
    if (i < 294912){                       // pimg
        int m = i / 98304, r = i % 98304;
        int c = r / 8192, rr = r % 8192;
        int col = rr >> 6, kb2 = rr & 63;
        int kb = kb2 ^ ((col & 7) << 3);
        pimg[i] = f2bf(proj_w[m*98304 + (c*64 + kb)*128 + col]);
    } else if (i < 688128){                // w1img
        int j = i - 294912;
        int e = j / 49152, r = j % 49152;
        int ph = r / 4096, rr = r % 4096;
        int q = rr >> 10, col = (rr >> 3) & 127, el = rr & 7;
        w1img[j] = f2bf(exp_w1[e*49152 + (ph*32 + q*8 + el)*128 + col]);
    } else if (i < 819200){                // w2img
        int j = i - 688128;
        int e = j / 16384, r = j % 16384;
        int c2 = r / 4096, rr = r % 4096;
        int q = rr >> 10, col = (rr >> 3) & 127, el = rr & 7;
        w2img[j] = f2bf(exp_w2[e*16384 + (c2*32 + q*8 + el)*128 + col]);
    } else if (i < 827392){                // prwT
        int j = i - 819200;
        int o = j / 128, k = j % 128;
        prwT[j] = f2bf(pre_w[k*64 + o]);
    } else if (i < 833536){                // gwimg
        int j = i - 827392;
        int e = j / 384, k = j % 384;
        gwimg[j] = (e < 8) ? f2bf(gate_w[k*8 + e]) : (u16)0;
    }
}

// ---------------- proj: tile 64 rows x 128 cols, BK=64, async dbuf ------------
// EXACT r4 version (linear xq output) — the measured-fast epilogue.
__global__ __launch_bounds__(256, 2) void proj_kernel(
    const float* __restrict__ ft, const float* __restrict__ fa, const float* __restrict__ fv,
    const u16* __restrict__ pimg, const float* __restrict__ proj_b,
    u16* __restrict__ xq)
{
    __shared__ char lds[65536];            // 2 slots x (A 16KB + B 16KB)
    const int m = blockIdx.y;
    const float* feat = (m == 0) ? ft : (m == 1) ? fa : fv;
    const int row0 = blockIdx.x * 64;
    const int tid  = threadIdx.x;
    const int lane = tid & 63, wid = tid >> 6;
    const int wr = wid >> 1, wc = wid & 1;
    const int lr = lane & 15, q = lane >> 4, r4 = q * 4;

    u32 aoffs[4];
    #pragma unroll
    for (int i = 0; i < 4; i++){
        int P = i*4096 + wid*1024 + lane*16;
        int row = P >> 8, inner = P & 255;
        aoffs[i] = (u32)((row0 + row)*3072 + (inner ^ ((row & 7) << 4)));
    }
    const char* abase = (const char*)feat;
    const char* bbase = (const char*)pimg + (size_t)m * 196608 + wid*1024 + lane*16;
    const int ldsP = wid*1024 + lane*16;

    f32x4 acc[2][4];
    #pragma unroll
    for (int i = 0; i < 2; i++)
        #pragma unroll
        for (int j = 0; j < 4; j++) acc[i][j] = {0.f, 0.f, 0.f, 0.f};

#define STAGE(s, c) do{                                                        \
        char* la = lds + (s)*32768 + ldsP;                                     \
        char* lb = lds + (s)*32768 + 16384 + ldsP;                             \
        const char* gb = bbase + (c)*16384;                                    \
        u32 kadd = (u32)(c) << 8;                                              \
        _Pragma("unroll")                                                      \
        for (int i = 0; i < 4; i++) async_cp16(la + i*4096, abase + aoffs[i] + kadd); \
        _Pragma("unroll")                                                      \
        for (int i = 0; i < 4; i++) async_cp16(lb + i*4096, gb + i*4096);      \
    }while(0)

#define CONSUME(s) do{                                                         \
        const char* Abuf = lds + (s)*32768;                                    \
        const char* Bbuf = Abuf + 16384;                                       \
        _Pragma("unroll")                                                      \
        for (int ks = 0; ks < 2; ks++){                                        \
            bf16x8 af[2];                                                      \
            _Pragma("unroll")                                                  \
            for (int mi = 0; mi < 2; mi++){                                    \
                int row = wr*32 + mi*16 + lr;                                  \
                int aoff = row*256 + ((ks*128 + q*32) ^ ((row & 7) << 4));     \
                f32x4 a0 = *(const f32x4*)(Abuf + aoff);                       \
                f32x4 a1 = *(const f32x4*)(Abuf + (aoff ^ 16));                \
                union { u32 w[4]; bf16x8 v; } u;                               \
                u.w[0] = cvtpk(a0.x, a0.y); u.w[1] = cvtpk(a0.z, a0.w);        \
                u.w[2] = cvtpk(a1.x, a1.y); u.w[3] = cvtpk(a1.z, a1.w);        \
                af[mi] = u.v;                                                  \
            }                                                                  \
            _Pragma("unroll")                                                  \
            for (int ni = 0; ni < 4; ni++){                                    \
                int col = wc*64 + ni*16 + lr;                                  \
                int boff = col*128 + ((ks*64 + q*16) ^ ((col & 7) << 4));      \
                bf16x8 bf = *(const bf16x8*)(Bbuf + boff);                     \
                acc[0][ni] = __builtin_amdgcn_mfma_f32_16x16x32_bf16(af[0], bf, acc[0][ni], 0, 0, 0); \
                acc[1][ni] = __builtin_amdgcn_mfma_f32_16x16x32_bf16(af[1], bf, acc[1][ni], 0, 0, 0); \
            }                                                                  \
        }                                                                      \
    }while(0)

    STAGE(0, 0);
    int cur = 0;
    for (int t = 0; t < 11; t++){
        __builtin_amdgcn_sched_barrier(0);
        __builtin_amdgcn_s_barrier();
        STAGE(cur ^ 1, t + 1);
        asm volatile("s_waitcnt vmcnt(8)" ::: "memory");
        __builtin_amdgcn_s_barrier();
        __builtin_amdgcn_sched_barrier(0);
        CONSUME(cur);
        cur ^= 1;
    }
    __builtin_amdgcn_sched_barrier(0);
    __builtin_amdgcn_s_barrier();
    asm volatile("s_waitcnt vmcnt(0)" ::: "memory");
    __builtin_amdgcn_s_barrier();
    __builtin_amdgcn_sched_barrier(0);
    CONSUME(cur);
#undef STAGE
#undef CONSUME

    __syncthreads();
    u16 (*Os)[136] = (u16(*)[136])lds;
    #pragma unroll
    for (int mi = 0; mi < 2; mi++)
        #pragma unroll
        for (int ni = 0; ni < 4; ni++){
            int col = wc*64 + ni*16 + lr;
            float bias = proj_b[m*128 + col];
            #pragma unroll
            for (int j = 0; j < 4; j++)
                Os[wr*32 + mi*16 + r4 + j][col] = f2bf(acc[mi][ni][j] + bias);
        }
    __syncthreads();
    {
        int row = tid >> 2, cg = (tid & 3) * 32;
        u16* dst = xq + (size_t)(row0 + row) * 384 + m*128 + cg;
        #pragma unroll
        for (int i = 0; i < 4; i++)
            *(uint4*)(dst + i*8) = *(uint4*)&Os[row][cg + i*8];
    }
}

// ---------------- fused gate + experts + pre + head ---------------------------
// M=128 tile, 512 threads (8 waves 4x2), grid 256 (1 block/CU).
// Xs image filled by reg-staging from LINEAR xq (coalesced reads + computed
// ds_write positions); weights staged via global_load_lds counted-vmcnt pipeline.
#define XS_OFF   0
#define WB_OFF   98304
#define HS_OFF   114688
#define GWT_OFF  149504
#define B1_OFF   153600
#define B2_OFF   155648

__global__ __launch_bounds__(512, 2) void moe_kernel(
    const u16* __restrict__ xq, const u16* __restrict__ w1img, const u16* __restrict__ w2img,
    const u16* __restrict__ prwT, const u16* __restrict__ gwimg,
    const float* __restrict__ gate_b, const float* __restrict__ exp_b1, const float* __restrict__ exp_b2,
    const float* __restrict__ pre_b, const float* __restrict__ head_w, const float* __restrict__ head_b,
    float* __restrict__ out)
{
    __shared__ __align__(16) char lds[157696];
    const int tid = threadIdx.x;
    const int lane = tid & 63, wid = tid >> 6;   // 8 waves
    const int wr = wid >> 1, wc = wid & 1;       // 4 x 2
    const int lr = lane & 15, q = lane >> 4;
    const int blk = blockIdx.x;
    const char* w1b = (const char*)w1img;
    const char* w2b = (const char*)w2img;
    u16* Hs  = (u16*)(lds + HS_OFF);             // [128][136]
    u16* b1L = (u16*)(lds + B1_OFF);
    u16* b2L = (u16*)(lds + B2_OFF);

    // ---- prologue: reg-stage Xs image from linear xq; chunk0 + biases ----
    {
        const char* xg = (const char*)xq + (size_t)blk * 98304;
        #pragma unroll
        for (int i = 0; i < 12; i++){
            int P = i*8192 + tid*16;
            uint4 v = *(const uint4*)(xg + P);
            int row128 = P / 768;
            int kbyte  = P - row128*768;
            int dst = (row128 >> 6)*49152 + (kbyte >> 6)*4096
                    + ((kbyte >> 4) & 3)*1024 + (row128 & 63)*16;
            *(uint4*)(lds + dst) = v;
        }
        async_cp16(lds + WB_OFF + tid*16, w1b + tid*16);   // chunk 0 = e0/ph0
        for (int i = tid; i < 1024; i += 512){
            b1L[i] = f2bf(exp_b1[i]);
            b2L[i] = f2bf(exp_b2[i]);
        }
    }
    asm volatile("s_waitcnt vmcnt(0) lgkmcnt(0)" ::: "memory");
    __builtin_amdgcn_sched_barrier(0);
    __builtin_amdgcn_s_barrier();

    // ---- gate: one MFMA column per wave (16 rows), softmax over 8 lanes ----
    {
        f32x4 ga = {0.f, 0.f, 0.f, 0.f};
        const char* xb = lds + (wid >> 2)*49152 + ((wid & 3)*16 + lr)*16 + q*1024;
        const u16* gwp = gwimg + lr*384 + q*8;
        #pragma unroll
        for (int kt = 0; kt < 12; kt++){
            bf16x8 af = *(const bf16x8*)(xb + kt*4096);
            bf16x8 gb = *(const bf16x8*)(gwp + kt*32);
            ga = __builtin_amdgcn_mfma_f32_16x16x32_bf16(af, gb, ga, 0, 0, 0);
        }
        float gbv = gate_b[lr & 7];
        float gw4[4];
        #pragma unroll
        for (int j = 0; j < 4; j++){
            float v = ga[j] + gbv;
            float mx = v;
            mx = fmaxf(mx, __shfl_xor(mx, 1));
            mx = fmaxf(mx, __shfl_xor(mx, 2));
            mx = fmaxf(mx, __shfl_xor(mx, 4));
            float s = __expf(v - mx);
            float t = s;
            t += __shfl_xor(t, 1);
            t += __shfl_xor(t, 2);
            t += __shfl_xor(t, 4);
            gw4[j] = s / t;
        }
        if (lr < 8){
            f32x4 wv = {gw4[0], gw4[1], gw4[2], gw4[3]};
            *(f32x4*)(lds + GWT_OFF + lr*512 + (wid*16 + q*4)*4) = wv;
        }
    }
    asm volatile("s_waitcnt lgkmcnt(0)" ::: "memory");
    __builtin_amdgcn_sched_barrier(0);
    __builtin_amdgcn_s_barrier();

    // ---- expert pipeline: 128 chunks, dbuf, counted vmcnt ----
    f32x4 fus[2][4];
    #pragma unroll
    for (int i = 0; i < 2; i++)
        #pragma unroll
        for (int j = 0; j < 4; j++) fus[i][j] = {0.f, 0.f, 0.f, 0.f};
    int cur = 0;

    #pragma unroll 1
    for (int e = 0; e < 8; e++){
        f32x4 acc[2][4];
        #pragma unroll
        for (int i = 0; i < 2; i++)
            #pragma unroll
            for (int j = 0; j < 4; j++) acc[i][j] = {0.f, 0.f, 0.f, 0.f};

        #pragma unroll 1
        for (int ph = 0; ph < 12; ph++){
            __builtin_amdgcn_sched_barrier(0);
            __builtin_amdgcn_s_barrier();
            {   // stage chunk g+1 (max 124 here, always valid)
                int gn = e*16 + ph + 1;
                int en = gn >> 4, pn = gn & 15;
                const char* src = (pn < 12) ? (w1b + en*98304 + pn*8192)
                                            : (w2b + en*32768 + (pn - 12)*8192);
                async_cp16(lds + WB_OFF + (cur ^ 1)*8192 + tid*16, src + tid*16);
            }
            asm volatile("s_waitcnt vmcnt(1)" ::: "memory");
            __builtin_amdgcn_s_barrier();
            __builtin_amdgcn_sched_barrier(0);
            const char* wsl = lds + WB_OFF + cur*8192 + q*2048;
            const char* xa  = lds + (wr >> 1)*49152 + ph*4096 + q*1024;
            bf16x8 af0 = *(const bf16x8*)(xa + ((wr & 1)*32 + lr)*16);
            bf16x8 af1 = *(const bf16x8*)(xa + ((wr & 1)*32 + 16 + lr)*16);
            #pragma unroll
            for (int ni = 0; ni < 4; ni++){
                bf16x8 bf = *(const bf16x8*)(wsl + (wc*64 + ni*16 + lr)*16);
                acc[0][ni] = __builtin_amdgcn_mfma_f32_16x16x32_bf16(af0, bf, acc[0][ni], 0, 0, 0);
                acc[1][ni] = __builtin_amdgcn_mfma_f32_16x16x32_bf16(af1, bf, acc[1][ni], 0, 0, 0);
            }
            cur ^= 1;
        }
        // h = relu(acc + b1) -> Hs
        #pragma unroll
        for (int mi = 0; mi < 2; mi++)
            #pragma unroll
            for (int ni = 0; ni < 4; ni++){
                int col = wc*64 + ni*16 + lr;
                float b1v = bf2f(b1L[e*128 + col]);
                #pragma unroll
                for (int j = 0; j < 4; j++){
                    int row = wr*32 + mi*16 + q*4 + j;
                    Hs[row*136 + col] = f2bf(fmaxf(acc[mi][ni][j] + b1v, 0.f));
                }
            }
        asm volatile("s_waitcnt lgkmcnt(0)" ::: "memory");
        __builtin_amdgcn_sched_barrier(0);

        f32x4 ac2[2][4];
        #pragma unroll
        for (int i = 0; i < 2; i++)
            #pragma unroll
            for (int j = 0; j < 4; j++) ac2[i][j] = {0.f, 0.f, 0.f, 0.f};

        #pragma unroll 1
        for (int p2 = 0; p2 < 4; p2++){
            __builtin_amdgcn_sched_barrier(0);
            __builtin_amdgcn_s_barrier();
            {   // stage chunk g+1 (clamp -> dummy restage of 127 at the very end)
                int gn = e*16 + 13 + p2;
                if (gn > 127) gn = 127;
                int en = gn >> 4, pn = gn & 15;
                const char* src = (pn < 12) ? (w1b + en*98304 + pn*8192)
                                            : (w2b + en*32768 + (pn - 12)*8192);
                async_cp16(lds + WB_OFF + (cur ^ 1)*8192 + tid*16, src + tid*16);
            }
            asm volatile("s_waitcnt vmcnt(1)" ::: "memory");
            __builtin_amdgcn_s_barrier();
            __builtin_amdgcn_sched_barrier(0);
            const char* wsl = lds + WB_OFF + cur*8192 + q*2048;
            const char* hb  = (const char*)Hs + (p2*32 + q*8)*2;
            bf16x8 af0 = *(const bf16x8*)(hb + (wr*32 + lr)*272);
            bf16x8 af1 = *(const bf16x8*)(hb + (wr*32 + 16 + lr)*272);
            #pragma unroll
            for (int ni = 0; ni < 4; ni++){
                bf16x8 bf = *(const bf16x8*)(wsl + (wc*64 + ni*16 + lr)*16);
                ac2[0][ni] = __builtin_amdgcn_mfma_f32_16x16x32_bf16(af0, bf, ac2[0][ni], 0, 0, 0);
                ac2[1][ni] = __builtin_amdgcn_mfma_f32_16x16x32_bf16(af1, bf, ac2[1][ni], 0, 0, 0);
            }
            cur ^= 1;
        }
        // fused += gw[:,e] * (eo + b2)
        #pragma unroll
        for (int mi = 0; mi < 2; mi++){
            f32x4 gwv = *(const f32x4*)(lds + GWT_OFF + e*512 + (wr*32 + mi*16 + q*4)*4);
            #pragma unroll
            for (int ni = 0; ni < 4; ni++){
                int col = wc*64 + ni*16 + lr;
                float b2v = bf2f(b2L[e*128 + col]);
                #pragma unroll
                for (int j = 0; j < 4; j++)
                    fus[mi][ni][j] += gwv[j] * (ac2[mi][ni][j] + b2v);
            }
        }
    }

    asm volatile("s_waitcnt vmcnt(0)" ::: "memory");   // drain dummy stage
    __builtin_amdgcn_sched_barrier(0);
    __builtin_amdgcn_s_barrier();                      // all Hs(h7) reads done
    // fused -> Hs (bf16)
    #pragma unroll
    for (int mi = 0; mi < 2; mi++)
        #pragma unroll
        for (int ni = 0; ni < 4; ni++){
            int col = wc*64 + ni*16 + lr;
            #pragma unroll
            for (int j = 0; j < 4; j++){
                int row = wr*32 + mi*16 + q*4 + j;
                Hs[row*136 + col] = f2bf(fus[mi][ni][j]);
            }
        }
    asm volatile("s_waitcnt lgkmcnt(0)" ::: "memory");
    __builtin_amdgcn_sched_barrier(0);
    __builtin_amdgcn_s_barrier();

    // ---- penult = relu(fused @ pre_w + pre_b): wave wid -> rows wid*16..+16 ----
    f32x4 ap[4];
    #pragma unroll
    for (int i = 0; i < 4; i++) ap[i] = {0.f, 0.f, 0.f, 0.f};
    #pragma unroll
    for (int kt = 0; kt < 4; kt++){
        bf16x8 af = *(const bf16x8*)((const char*)Hs + (wid*16 + lr)*272 + (kt*32 + q*8)*2);
        #pragma unroll
        for (int ni = 0; ni < 4; ni++){
            bf16x8 bf = *(const bf16x8*)(prwT + (size_t)(ni*16 + lr)*128 + kt*32 + q*8);
            ap[ni] = __builtin_amdgcn_mfma_f32_16x16x32_bf16(af, bf, ap[ni], 0, 0, 0);
        }
    }
    float* Pen = (float*)lds;   // [128][68], Xs region dead
    #pragma unroll
    for (int ni = 0; ni < 4; ni++){
        int col = ni*16 + lr;
        float pbv = pre_b[col];
        #pragma unroll
        for (int j = 0; j < 4; j++){
            int row = wid*16 + q*4 + j;
            Pen[row*68 + col] = fmaxf(ap[ni][j] + pbv, 0.f);
        }
    }
    asm volatile("s_waitcnt lgkmcnt(0)" ::: "memory");
    __builtin_amdgcn_sched_barrier(0);
    __builtin_amdgcn_s_barrier();
    // ---- head ----
    if (tid < 256){
        int r = tid >> 1, c = tid & 1;
        float s = head_b[c];
        #pragma unroll 8
        for (int k = 0; k < 64; k++) s += Pen[r*68 + k] * head_w[k*2 + c];
        out[(size_t)(blk*128 + r)*2 + c] = s;
    }
}

extern "C" void kernel_launch(void* const* d_in, const int* in_sizes, int n_in,
                              void* d_out, int out_size, void* d_ws, size_t ws_size,
                              hipStream_t stream) {
    const float* ft     = (const float*)d_in[0];
    const float* fa     = (const float*)d_in[1];
    const float* fv     = (const float*)d_in[2];
    const float* proj_w = (const float*)d_in[3];
    const float* proj_b = (const float*)d_in[4];
    const float* exp_w1 = (const float*)d_in[5];
    const float* exp_b1 = (const float*)d_in[6];
    const float* exp_w2 = (const float*)d_in[7];
    const float* exp_b2 = (const float*)d_in[8];
    const float* gate_w = (const float*)d_in[9];
    const float* gate_b = (const float*)d_in[10];
    const float* pre_w  = (const float*)d_in[11];
    const float* pre_b  = (const float*)d_in[12];
    const float* head_w = (const float*)d_in[13];
    const float* head_b = (const float*)d_in[14];
    float* out = (float*)d_out;

    u16* xq    = (u16*)d_ws;                      // 32768*384
    u16* pimg  = xq + (size_t)B_ROWS * 384;       // 294912
    u16* w1img = pimg + 294912;                   // 393216
    u16* w2img = w1img + 393216;                  // 131072
    u16* prwT  = w2img + 131072;                  // 8192
    u16* gwimg = prwT + 8192;                     // 6144

    cast_weights_kernel<<<3256, 256, 0, stream>>>(proj_w, exp_w1, exp_w2, pre_w, gate_w,
                                                  pimg, w1img, w2img, prwT, gwimg);
    proj_kernel<<<dim3(B_ROWS/64, 3), 256, 0, stream>>>(ft, fa, fv, pimg, proj_b, xq);
    moe_kernel<<<256, 512, 0, stream>>>(xq, w1img, w2img, prwT, gwimg,
                                        gate_b, exp_b1, exp_b2,
                                        pre_b, head_w, head_b, out);
}

// Round 7
// 140.613 us; speedup vs baseline: 1.0001x; 1.0001x over previous
//
#include <hip/hip_runtime.h>
#include <hip/hip_bf16.h>

#define B_ROWS 32768

typedef unsigned short u16;
typedef unsigned int u32;
typedef float f32x4 __attribute__((ext_vector_type(4)));
typedef __bf16 bf16x8 __attribute__((ext_vector_type(8)));

__device__ __forceinline__ u16 f2bf(float f){
    union { float f; u32 u; } v; v.f = f;
    return (u16)((v.u + 0x7FFFu + ((v.u >> 16) & 1u)) >> 16);
}
__device__ __forceinline__ float bf2f(u16 h){
    union { u32 u; float f; } v; v.u = ((u32)h) << 16; return v.f;
}
// v_cvt_pk_bf16_f32: dst.lo = bf16(lo), dst.hi = bf16(hi), RNE
__device__ __forceinline__ u32 cvtpk(float lo, float hi){
    u32 r;
    asm("v_cvt_pk_bf16_f32 %0, %1, %2" : "=v"(r) : "v"(lo), "v"(hi));
    return r;
}
__device__ __forceinline__ void async_cp16(void* lds_dst, const void* g_src){
    __builtin_amdgcn_global_load_lds(
        (const __attribute__((address_space(1))) unsigned int*)g_src,
        (__attribute__((address_space(3))) unsigned int*)lds_dst, 16, 0, 0);
}

// ---------------- weight cast/transpose into staging-friendly images ----------
// pimg : [3][24][4096 u16]  XOR-swizzled proj-B LDS chunk image (BK=32):
//        within chunk: col = rr>>5, kk = rr&31, kb = kk ^ (((col>>1)&3)<<3)
// w1img: [8][12 chunks][q:4][col:128][8]  (chunk ph covers k = ph*32 + q*8 + el)
// w2img: [8][4 chunks][q:4][col:128][8]
// prwT : [64][128] plain [o][k]
// gwimg: [16][384] zero-padded gate weights, [e][k]
__global__ void cast_weights_kernel(const float* __restrict__ proj_w,
                                    const float* __restrict__ exp_w1,
                                    const float* __restrict__ exp_w2,
                                    const float* __restrict__ pre_w,
                                    const float* __restrict__ gate_w,
                                    u16* __restrict__ pimg, u16* __restrict__ w1img,
                                    u16* __restrict__ w2img, u16* __restrict__ prwT,
                                    u16* __restrict__ gwimg){
    int i = blockIdx.x * 256 + threadIdx.x;
    if (i < 294912){                       // pimg (BK=32 chunks)
        int m = i / 98304, r = i % 98304;
        int c = r / 4096, rr = r % 4096;
        int col = rr >> 5, kk = rr & 31;
        int kb = kk ^ (((col >> 1) & 3) << 3);
        pimg[i] = f2bf(proj_w[m*98304 + (c*32 + kb)*128 + col]);
    } else if (i < 688128){                // w1img
        int j = i - 294912;
        int e = j / 49152, r = j % 49152;
        int ph = r / 4096, rr = r % 4096;
        int q = rr >> 10, col = (rr >> 3) & 127, el = rr & 7;
        w1img[j] = f2bf(exp_w1[e*49152 + (ph*32 + q*8 + el)*128 + col]);
    } else if (i < 819200){                // w2img
        int j = i - 688128;
        int e = j / 16384, r = j % 16384;
        int c2 = r / 4096, rr = r % 4096;
        int q = rr >> 10, col = (rr >> 3) & 127, el = rr & 7;
        w2img[j] = f2bf(exp_w2[e*16384 + (c2*32 + q*8 + el)*128 + col]);
    } else if (i < 827392){                // prwT
        int j = i - 819200;
        int o = j / 128, k = j % 128;
        prwT[j] = f2bf(pre_w[k*64 + o]);
    } else if (i < 833536){                // gwimg
        int j = i - 827392;
        int e = j / 384, k = j % 384;
        gwimg[j] = (e < 8) ? f2bf(gate_w[k*8 + e]) : (u16)0;
    }
}

// ---------------- proj: tile 64 rows x 128 cols, BK=32, async dbuf ------------
// LDS 32KB (2 slots x (A 8KB + B 8KB)) -> 4-5 blocks/CU for latency hiding.
// A: per-lane XOR-pre-swizzled f32 source addresses (linear LDS dest);
// B: pre-swizzled pimg chunks. Counted vmcnt(4) keeps next chunk in flight.
__global__ __launch_bounds__(256, 4) void proj_kernel(
    const float* __restrict__ ft, const float* __restrict__ fa, const float* __restrict__ fv,
    const u16* __restrict__ pimg, const float* __restrict__ proj_b,
    u16* __restrict__ xq)
{
    __shared__ char lds[32768];
    const int m = blockIdx.y;
    const float* feat = (m == 0) ? ft : (m == 1) ? fa : fv;
    const int row0 = blockIdx.x * 64;
    const int tid  = threadIdx.x;
    const int lane = tid & 63, wid = tid >> 6;
    const int wr = wid >> 1, wc = wid & 1;
    const int lr = lane & 15, q = lane >> 4, r4 = q * 4;

    // A staging source offsets: LDS byte P=(i*4096+tid*16) -> row=P>>7, inner=P&127
    u32 aoffs[2];
    #pragma unroll
    for (int i = 0; i < 2; i++){
        int P = i*4096 + tid*16;
        int row = P >> 7, inner = P & 127;
        aoffs[i] = (u32)((row0 + row)*3072 + (inner ^ ((row & 7) << 4)));
    }
    const char* abase = (const char*)feat;
    const char* bbase = (const char*)pimg + (size_t)m * 196608 + tid*16;

    f32x4 acc[2][4];
    #pragma unroll
    for (int i = 0; i < 2; i++)
        #pragma unroll
        for (int j = 0; j < 4; j++) acc[i][j] = {0.f, 0.f, 0.f, 0.f};

#define STAGE(s, c) do{                                                        \
        char* la = lds + (s)*16384 + tid*16;                                   \
        char* lb = lds + (s)*16384 + 8192 + tid*16;                            \
        const char* gb = bbase + (c)*8192;                                     \
        u32 kadd = (u32)(c) << 7;                                              \
        _Pragma("unroll")                                                      \
        for (int i = 0; i < 2; i++) async_cp16(la + i*4096, abase + aoffs[i] + kadd); \
        _Pragma("unroll")                                                      \
        for (int i = 0; i < 2; i++) async_cp16(lb + i*4096, gb + i*4096);      \
    }while(0)

#define CONSUME(s) do{                                                         \
        const char* Abuf = lds + (s)*16384;                                    \
        const char* Bbuf = Abuf + 8192;                                        \
        bf16x8 af[2];                                                          \
        _Pragma("unroll")                                                      \
        for (int mi = 0; mi < 2; mi++){                                        \
            int row = wr*32 + mi*16 + lr;                                      \
            int aoff = row*128 + ((q*32) ^ ((row & 7) << 4));                  \
            f32x4 a0 = *(const f32x4*)(Abuf + aoff);                           \
            f32x4 a1 = *(const f32x4*)(Abuf + (aoff ^ 16));                    \
            union { u32 w[4]; bf16x8 v; } u;                                   \
            u.w[0] = cvtpk(a0.x, a0.y); u.w[1] = cvtpk(a0.z, a0.w);            \
            u.w[2] = cvtpk(a1.x, a1.y); u.w[3] = cvtpk(a1.z, a1.w);            \
            af[mi] = u.v;                                                      \
        }                                                                      \
        _Pragma("unroll")                                                      \
        for (int ni = 0; ni < 4; ni++){                                        \
            int col = wc*64 + ni*16 + lr;                                      \
            int boff = col*64 + ((q*16) ^ (((col >> 1) & 3) << 4));            \
            bf16x8 bf = *(const bf16x8*)(Bbuf + boff);                         \
            acc[0][ni] = __builtin_amdgcn_mfma_f32_16x16x32_bf16(af[0], bf, acc[0][ni], 0, 0, 0); \
            acc[1][ni] = __builtin_amdgcn_mfma_f32_16x16x32_bf16(af[1], bf, acc[1][ni], 0, 0, 0); \
        }                                                                      \
    }while(0)

    STAGE(0, 0);
    int cur = 0;
    for (int t = 0; t < 23; t++){
        __builtin_amdgcn_sched_barrier(0);
        __builtin_amdgcn_s_barrier();                      // reads of slot cur^1 done
        STAGE(cur ^ 1, t + 1);
        asm volatile("s_waitcnt vmcnt(4)" ::: "memory");   // chunk t landed
        __builtin_amdgcn_s_barrier();
        __builtin_amdgcn_sched_barrier(0);
        CONSUME(cur);
        cur ^= 1;
    }
    __builtin_amdgcn_sched_barrier(0);
    __builtin_amdgcn_s_barrier();
    asm volatile("s_waitcnt vmcnt(0)" ::: "memory");
    __builtin_amdgcn_s_barrier();
    __builtin_amdgcn_sched_barrier(0);
    CONSUME(cur);
#undef STAGE
#undef CONSUME

    // epilogue: stage bf16 tile in LDS, then coalesced 64B/lane stores
    __syncthreads();
    u16 (*Os)[136] = (u16(*)[136])lds;
    #pragma unroll
    for (int mi = 0; mi < 2; mi++)
        #pragma unroll
        for (int ni = 0; ni < 4; ni++){
            int col = wc*64 + ni*16 + lr;
            float bias = proj_b[m*128 + col];
            #pragma unroll
            for (int j = 0; j < 4; j++)
                Os[wr*32 + mi*16 + r4 + j][col] = f2bf(acc[mi][ni][j] + bias);
        }
    __syncthreads();
    {
        int row = tid >> 2, cg = (tid & 3) * 32;
        u16* dst = xq + (size_t)(row0 + row) * 384 + m*128 + cg;
        #pragma unroll
        for (int i = 0; i < 4; i++)
            *(uint4*)(dst + i*8) = *(uint4*)&Os[row][cg + i*8];
    }
}

// ---------------- fused gate + experts + pre + head ---------------------------
// M=128 tile, 512 threads (8 waves 4x2), grid 256 (1 block/CU). Unchanged (r6).
#define XS_OFF   0
#define WB_OFF   98304
#define HS_OFF   114688
#define GWT_OFF  149504
#define B1_OFF   153600
#define B2_OFF   155648

__global__ __launch_bounds__(512, 2) void moe_kernel(
    const u16* __restrict__ xq, const u16* __restrict__ w1img, const u16* __restrict__ w2img,
    const u16* __restrict__ prwT, const u16* __restrict__ gwimg,
    const float* __restrict__ gate_b, const float* __restrict__ exp_b1, const float* __restrict__ exp_b2,
    const float* __restrict__ pre_b, const float* __restrict__ head_w, const float* __restrict__ head_b,
    float* __restrict__ out)
{
    __shared__ __align__(16) char lds[157696];
    const int tid = threadIdx.x;
    const int lane = tid & 63, wid = tid >> 6;   // 8 waves
    const int wr = wid >> 1, wc = wid & 1;       // 4 x 2
    const int lr = lane & 15, q = lane >> 4;
    const int blk = blockIdx.x;
    const char* w1b = (const char*)w1img;
    const char* w2b = (const char*)w2img;
    u16* Hs  = (u16*)(lds + HS_OFF);             // [128][136]
    u16* b1L = (u16*)(lds + B1_OFF);
    u16* b2L = (u16*)(lds + B2_OFF);

    // ---- prologue: reg-stage Xs image from linear xq; chunk0 + biases ----
    {
        const char* xg = (const char*)xq + (size_t)blk * 98304;
        #pragma unroll
        for (int i = 0; i < 12; i++){
            int P = i*8192 + tid*16;
            uint4 v = *(const uint4*)(xg + P);
            int row128 = P / 768;
            int kbyte  = P - row128*768;
            int dst = (row128 >> 6)*49152 + (kbyte >> 6)*4096
                    + ((kbyte >> 4) & 3)*1024 + (row128 & 63)*16;
            *(uint4*)(lds + dst) = v;
        }
        async_cp16(lds + WB_OFF + tid*16, w1b + tid*16);   // chunk 0 = e0/ph0
        for (int i = tid; i < 1024; i += 512){
            b1L[i] = f2bf(exp_b1[i]);
            b2L[i] = f2bf(exp_b2[i]);
        }
    }
    asm volatile("s_waitcnt vmcnt(0) lgkmcnt(0)" ::: "memory");
    __builtin_amdgcn_sched_barrier(0);
    __builtin_amdgcn_s_barrier();

    // ---- gate: one MFMA column per wave (16 rows), softmax over 8 lanes ----
    {
        f32x4 ga = {0.f, 0.f, 0.f, 0.f};
        const char* xb = lds + (wid >> 2)*49152 + ((wid & 3)*16 + lr)*16 + q*1024;
        const u16* gwp = gwimg + lr*384 + q*8;
        #pragma unroll
        for (int kt = 0; kt < 12; kt++){
            bf16x8 af = *(const bf16x8*)(xb + kt*4096);
            bf16x8 gb = *(const bf16x8*)(gwp + kt*32);
            ga = __builtin_amdgcn_mfma_f32_16x16x32_bf16(af, gb, ga, 0, 0, 0);
        }
        float gbv = gate_b[lr & 7];
        float gw4[4];
        #pragma unroll
        for (int j = 0; j < 4; j++){
            float v = ga[j] + gbv;
            float mx = v;
            mx = fmaxf(mx, __shfl_xor(mx, 1));
            mx = fmaxf(mx, __shfl_xor(mx, 2));
            mx = fmaxf(mx, __shfl_xor(mx, 4));
            float s = __expf(v - mx);
            float t = s;
            t += __shfl_xor(t, 1);
            t += __shfl_xor(t, 2);
            t += __shfl_xor(t, 4);
            gw4[j] = s / t;
        }
        if (lr < 8){
            f32x4 wv = {gw4[0], gw4[1], gw4[2], gw4[3]};
            *(f32x4*)(lds + GWT_OFF + lr*512 + (wid*16 + q*4)*4) = wv;
        }
    }
    asm volatile("s_waitcnt lgkmcnt(0)" ::: "memory");
    __builtin_amdgcn_sched_barrier(0);
    __builtin_amdgcn_s_barrier();

    // ---- expert pipeline: 128 chunks, dbuf, counted vmcnt ----
    f32x4 fus[2][4];
    #pragma unroll
    for (int i = 0; i < 2; i++)
        #pragma unroll
        for (int j = 0; j < 4; j++) fus[i][j] = {0.f, 0.f, 0.f, 0.f};
    int cur = 0;

    #pragma unroll 1
    for (int e = 0; e < 8; e++){
        f32x4 acc[2][4];
        #pragma unroll
        for (int i = 0; i < 2; i++)
            #pragma unroll
            for (int j = 0; j < 4; j++) acc[i][j] = {0.f, 0.f, 0.f, 0.f};

        #pragma unroll 1
        for (int ph = 0; ph < 12; ph++){
            __builtin_amdgcn_sched_barrier(0);
            __builtin_amdgcn_s_barrier();
            {   // stage chunk g+1 (max 124 here, always valid)
                int gn = e*16 + ph + 1;
                int en = gn >> 4, pn = gn & 15;
                const char* src = (pn < 12) ? (w1b + en*98304 + pn*8192)
                                            : (w2b + en*32768 + (pn - 12)*8192);
                async_cp16(lds + WB_OFF + (cur ^ 1)*8192 + tid*16, src + tid*16);
            }
            asm volatile("s_waitcnt vmcnt(1)" ::: "memory");
            __builtin_amdgcn_s_barrier();
            __builtin_amdgcn_sched_barrier(0);
            const char* wsl = lds + WB_OFF + cur*8192 + q*2048;
            const char* xa  = lds + (wr >> 1)*49152 + ph*4096 + q*1024;
            bf16x8 af0 = *(const bf16x8*)(xa + ((wr & 1)*32 + lr)*16);
            bf16x8 af1 = *(const bf16x8*)(xa + ((wr & 1)*32 + 16 + lr)*16);
            #pragma unroll
            for (int ni = 0; ni < 4; ni++){
                bf16x8 bf = *(const bf16x8*)(wsl + (wc*64 + ni*16 + lr)*16);
                acc[0][ni] = __builtin_amdgcn_mfma_f32_16x16x32_bf16(af0, bf, acc[0][ni], 0, 0, 0);
                acc[1][ni] = __builtin_amdgcn_mfma_f32_16x16x32_bf16(af1, bf, acc[1][ni], 0, 0, 0);
            }
            cur ^= 1;
        }
        // h = relu(acc + b1) -> Hs
        #pragma unroll
        for (int mi = 0; mi < 2; mi++)
            #pragma unroll
            for (int ni = 0; ni < 4; ni++){
                int col = wc*64 + ni*16 + lr;
                float b1v = bf2f(b1L[e*128 + col]);
                #pragma unroll
                for (int j = 0; j < 4; j++){
                    int row = wr*32 + mi*16 + q*4 + j;
                    Hs[row*136 + col] = f2bf(fmaxf(acc[mi][ni][j] + b1v, 0.f));
                }
            }
        asm volatile("s_waitcnt lgkmcnt(0)" ::: "memory");
        __builtin_amdgcn_sched_barrier(0);

        f32x4 ac2[2][4];
        #pragma unroll
        for (int i = 0; i < 2; i++)
            #pragma unroll
            for (int j = 0; j < 4; j++) ac2[i][j] = {0.f, 0.f, 0.f, 0.f};

        #pragma unroll 1
        for (int p2 = 0; p2 < 4; p2++){
            __builtin_amdgcn_sched_barrier(0);
            __builtin_amdgcn_s_barrier();
            {   // stage chunk g+1 (clamp -> dummy restage of 127 at the very end)
                int gn = e*16 + 13 + p2;
                if (gn > 127) gn = 127;
                int en = gn >> 4, pn = gn & 15;
                const char* src = (pn < 12) ? (w1b + en*98304 + pn*8192)
                                            : (w2b + en*32768 + (pn - 12)*8192);
                async_cp16(lds + WB_OFF + (cur ^ 1)*8192 + tid*16, src + tid*16);
            }
            asm volatile("s_waitcnt vmcnt(1)" ::: "memory");
            __builtin_amdgcn_s_barrier();
            __builtin_amdgcn_sched_barrier(0);
            const char* wsl = lds + WB_OFF + cur*8192 + q*2048;
            const char* hb  = (const char*)Hs + (p2*32 + q*8)*2;
            bf16x8 af0 = *(const bf16x8*)(hb + (wr*32 + lr)*272);
            bf16x8 af1 = *(const bf16x8*)(hb + (wr*32 + 16 + lr)*272);
            #pragma unroll
            for (int ni = 0; ni < 4; ni++){
                bf16x8 bf = *(const bf16x8*)(wsl + (wc*64 + ni*16 + lr)*16);
                ac2[0][ni] = __builtin_amdgcn_mfma_f32_16x16x32_bf16(af0, bf, ac2[0][ni], 0, 0, 0);
                ac2[1][ni] = __builtin_amdgcn_mfma_f32_16x16x32_bf16(af1, bf, ac2[1][ni], 0, 0, 0);
            }
            cur ^= 1;
        }
        // fused += gw[:,e] * (eo + b2)
        #pragma unroll
        for (int mi = 0; mi < 2; mi++){
            f32x4 gwv = *(const f32x4*)(lds + GWT_OFF + e*512 + (wr*32 + mi*16 + q*4)*4);
            #pragma unroll
            for (int ni = 0; ni < 4; ni++){
                int col = wc*64 + ni*16 + lr;
                float b2v = bf2f(b2L[e*128 + col]);
                #pragma unroll
                for (int j = 0; j < 4; j++)
                    fus[mi][ni][j] += gwv[j] * (ac2[mi][ni][j] + b2v);
            }
        }
    }

    asm volatile("s_waitcnt vmcnt(0)" ::: "memory");   // drain dummy stage
    __builtin_amdgcn_sched_barrier(0);
    __builtin_amdgcn_s_barrier();                      // all Hs(h7) reads done
    // fused -> Hs (bf16)
    #pragma unroll
    for (int mi = 0; mi < 2; mi++)
        #pragma unroll
        for (int ni = 0; ni < 4; ni++){
            int col = wc*64 + ni*16 + lr;
            #pragma unroll
            for (int j = 0; j < 4; j++){
                int row = wr*32 + mi*16 + q*4 + j;
                Hs[row*136 + col] = f2bf(fus[mi][ni][j]);
            }
        }
    asm volatile("s_waitcnt lgkmcnt(0)" ::: "memory");
    __builtin_amdgcn_sched_barrier(0);
    __builtin_amdgcn_s_barrier();

    // ---- penult = relu(fused @ pre_w + pre_b): wave wid -> rows wid*16..+16 ----
    f32x4 ap[4];
    #pragma unroll
    for (int i = 0; i < 4; i++) ap[i] = {0.f, 0.f, 0.f, 0.f};
    #pragma unroll
    for (int kt = 0; kt < 4; kt++){
        bf16x8 af = *(const bf16x8*)((const char*)Hs + (wid*16 + lr)*272 + (kt*32 + q*8)*2);
        #pragma unroll
        for (int ni = 0; ni < 4; ni++){
            bf16x8 bf = *(const bf16x8*)(prwT + (size_t)(ni*16 + lr)*128 + kt*32 + q*8);
            ap[ni] = __builtin_amdgcn_mfma_f32_16x16x32_bf16(af, bf, ap[ni], 0, 0, 0);
        }
    }
    float* Pen = (float*)lds;   // [128][68], Xs region dead
    #pragma unroll
    for (int ni = 0; ni < 4; ni++){
        int col = ni*16 + lr;
        float pbv = pre_b[col];
        #pragma unroll
        for (int j = 0; j < 4; j++){
            int row = wid*16 + q*4 + j;
            Pen[row*68 + col] = fmaxf(ap[ni][j] + pbv, 0.f);
        }
    }
    asm volatile("s_waitcnt lgkmcnt(0)" ::: "memory");
    __builtin_amdgcn_sched_barrier(0);
    __builtin_amdgcn_s_barrier();
    // ---- head ----
    if (tid < 256){
        int r = tid >> 1, c = tid & 1;
        float s = head_b[c];
        #pragma unroll 8
        for (int k = 0; k < 64; k++) s += Pen[r*68 + k] * head_w[k*2 + c];
        out[(size_t)(blk*128 + r)*2 + c] = s;
    }
}

extern "C" void kernel_launch(void* const* d_in, const int* in_sizes, int n_in,
                              void* d_out, int out_size, void* d_ws, size_t ws_size,
                              hipStream_t stream) {
    const float* ft     = (const float*)d_in[0];
    const float* fa     = (const float*)d_in[1];
    const float* fv     = (const float*)d_in[2];
    const float* proj_w = (const float*)d_in[3];
    const float* proj_b = (const float*)d_in[4];
    const float* exp_w1 = (const float*)d_in[5];
    const float* exp_b1 = (const float*)d_in[6];
    const float* exp_w2 = (const float*)d_in[7];
    const float* exp_b2 = (const float*)d_in[8];
    const float* gate_w = (const float*)d_in[9];
    const float* gate_b = (const float*)d_in[10];
    const float* pre_w  = (const float*)d_in[11];
    const float* pre_b  = (const float*)d_in[12];
    const float* head_w = (const float*)d_in[13];
    const float* head_b = (const float*)d_in[14];
    float* out = (float*)d_out;

    u16* xq    = (u16*)d_ws;                      // 32768*384
    u16* pimg  = xq + (size_t)B_ROWS * 384;       // 294912
    u16* w1img = pimg + 294912;                   // 393216
    u16* w2img = w1img + 393216;                  // 131072
    u16* prwT  = w2img + 131072;                  // 8192
    u16* gwimg = prwT + 8192;                     // 6144

    cast_weights_kernel<<<3256, 256, 0, stream>>>(proj_w, exp_w1, exp_w2, pre_w, gate_w,
                                                  pimg, w1img, w2img, prwT, gwimg);
    proj_kernel<<<dim3(B_ROWS/64, 3), 256, 0, stream>>>(ft, fa, fv, pimg, proj_b, xq);
    moe_kernel<<<256, 512, 0, stream>>>(xq, w1img, w2img, prwT, gwimg,
                                        gate_b, exp_b1, exp_b2,
                                        pre_b, head_w, head_b, out);
}

// Round 8
// 122.556 us; speedup vs baseline: 1.1474x; 1.1473x over previous
//
#include <hip/hip_runtime.h>
#include <hip/hip_bf16.h>

#define B_ROWS 32768

typedef unsigned short u16;
typedef unsigned int u32;
typedef float f32x4 __attribute__((ext_vector_type(4)));
typedef __bf16 bf16x8 __attribute__((ext_vector_type(8)));

__device__ __forceinline__ u16 f2bf(float f){
    union { float f; u32 u; } v; v.f = f;
    return (u16)((v.u + 0x7FFFu + ((v.u >> 16) & 1u)) >> 16);
}
__device__ __forceinline__ float bf2f(u16 h){
    union { u32 u; float f; } v; v.u = ((u32)h) << 16; return v.f;
}
__device__ __forceinline__ u32 cvtpk(float lo, float hi){
    u32 r;
    asm("v_cvt_pk_bf16_f32 %0, %1, %2" : "=v"(r) : "v"(lo), "v"(hi));
    return r;
}
__device__ __forceinline__ void async_cp16(void* lds_dst, const void* g_src){
    __builtin_amdgcn_global_load_lds(
        (const __attribute__((address_space(1))) unsigned int*)g_src,
        (__attribute__((address_space(3))) unsigned int*)lds_dst, 16, 0, 0);
}

// ---------------- weight cast/transpose into staging-friendly images ----------
// pimg : [3][24][4096 u16]  XOR-swizzled proj-B LDS chunk image (BK=32)
// w1img: [8][12 chunks][q:4][col:128][8]
// w2img: [8][4 chunks][q:4][col:128][8]
// prwT : [64][128] plain [o][k]
// gwimg: [16][384] zero-padded gate weights, [e][k]
__global__ void cast_weights_kernel(const float* __restrict__ proj_w,
                                    const float* __restrict__ exp_w1,
                                    const float* __restrict__ exp_w2,
                                    const float* __restrict__ pre_w,
                                    const float* __restrict__ gate_w,
                                    u16* __restrict__ pimg, u16* __restrict__ w1img,
                                    u16* __restrict__ w2img, u16* __restrict__ prwT,
                                    u16* __restrict__ gwimg){
    int i = blockIdx.x * 256 + threadIdx.x;
    if (i < 294912){                       // pimg (BK=32 chunks)
        int m = i / 98304, r = i % 98304;
        int c = r / 4096, rr = r % 4096;
        int col = rr >> 5, kk = rr & 31;
        int kb = kk ^ (((col >> 1) & 3) << 3);
        pimg[i] = f2bf(proj_w[m*98304 + (c*32 + kb)*128 + col]);
    } else if (i < 688128){                // w1img
        int j = i - 294912;
        int e = j / 49152, r = j % 49152;
        int ph = r / 4096, rr = r % 4096;
        int q = rr >> 10, col = (rr >> 3) & 127, el = rr & 7;
        w1img[j] = f2bf(exp_w1[e*49152 + (ph*32 + q*8 + el)*128 + col]);
    } else if (i < 819200){                // w2img
        int j = i - 688128;
        int e = j / 16384, r = j % 16384;
        int c2 = r / 4096, rr = r % 4096;
        int q = rr >> 10, col = (rr >> 3) & 127, el = rr & 7;
        w2img[j] = f2bf(exp_w2[e*16384 + (c2*32 + q*8 + el)*128 + col]);
    } else if (i < 827392){                // prwT
        int j = i - 819200;
        int o = j / 128, k = j % 128;
        prwT[j] = f2bf(pre_w[k*64 + o]);
    } else if (i < 833536){                // gwimg
        int j = i - 827392;
        int e = j / 384, k = j % 384;
        gwimg[j] = (e < 8) ? f2bf(gate_w[k*8 + e]) : (u16)0;
    }
}

// ---------------- fully fused: proj + gate + experts + pre + head -------------
// 256 blocks x 512 threads (8 waves 4x2), 128 rows per block, 1 block/CU.
// Phase A (proj): 72 chunks (3 modalities x 24 BK=32 chunks), async dbuf,
//   counted vmcnt(3); x written straight into the Xs LDS image (no global xq).
// Phase B: gate via MFMA + 8-lane softmax.
// Phase C: expert pipeline (128 x 8KB chunks, vmcnt(1)) + pre + head.
#define XS_OFF   0          // 96 KB  x image [half2][kt12][q4][row64][16B]
#define ST_OFF   98304      // proj stage: 2 slots x 24KB (A 16K + B 8K); dies after phase A
#define WB_OFF   98304      // expert weight dbuf 2 x 8KB (reuses stage area)
#define HS_OFF   114688     // [128][136] u16
#define GWT_OFF  149504     // gate weights f32 [8][128]; holds proj_b f32[384] during phase A
#define B1_OFF   153600
#define B2_OFF   155648

__global__ __launch_bounds__(512, 2) void fused_kernel(
    const float* __restrict__ ft, const float* __restrict__ fa, const float* __restrict__ fv,
    const u16* __restrict__ pimg, const float* __restrict__ proj_b,
    const u16* __restrict__ w1img, const u16* __restrict__ w2img,
    const u16* __restrict__ prwT, const u16* __restrict__ gwimg,
    const float* __restrict__ gate_b, const float* __restrict__ exp_b1, const float* __restrict__ exp_b2,
    const float* __restrict__ pre_b, const float* __restrict__ head_w, const float* __restrict__ head_b,
    float* __restrict__ out)
{
    __shared__ __align__(16) char lds[157696];
    const int tid = threadIdx.x;
    const int lane = tid & 63, wid = tid >> 6;   // 8 waves
    const int wr = wid >> 1, wc = wid & 1;       // 4 x 2
    const int lr = lane & 15, q = lane >> 4;
    const int blk = blockIdx.x;
    const int row0 = blk * 128;
    const char* w1b = (const char*)w1img;
    const char* w2b = (const char*)w2img;
    u16* Hs  = (u16*)(lds + HS_OFF);
    u16* b1L = (u16*)(lds + B1_OFF);
    u16* b2L = (u16*)(lds + B2_OFF);

    // ---- prologue: biases -> LDS, then drain vmcnt so pipeline counts are exact
    if (tid < 384) ((float*)(lds + GWT_OFF))[tid] = proj_b[tid];
    for (int i = tid; i < 1024; i += 512){
        b1L[i] = f2bf(exp_b1[i]);
        b2L[i] = f2bf(exp_b2[i]);
    }
    asm volatile("s_waitcnt vmcnt(0)" ::: "memory");

    // A staging source offsets (XOR-pre-swizzled global addresses, linear LDS dst)
    u32 aoffs[2];
    #pragma unroll
    for (int i = 0; i < 2; i++){
        int P = i*8192 + tid*16;
        int row = P >> 7, inner = P & 127;
        aoffs[i] = (u32)((row0 + row)*3072 + (inner ^ ((row & 7) << 4)));
    }

#define PSTAGE(s, c) do{                                                       \
        int mm = (c) / 24, kk = (c) % 24;                                      \
        const float* fb = (mm == 0) ? ft : (mm == 1) ? fa : fv;                \
        const char* ab = (const char*)fb;                                      \
        char* la = lds + ST_OFF + (s)*24576 + tid*16;                          \
        async_cp16(la,        ab + aoffs[0] + kk*128);                         \
        async_cp16(la + 8192, ab + aoffs[1] + kk*128);                         \
        async_cp16(lds + ST_OFF + (s)*24576 + 16384 + tid*16,                  \
                   (const char*)pimg + mm*196608 + kk*8192 + tid*16);          \
    }while(0)

#define PCONSUME(s) do{                                                        \
        const char* Abuf = lds + ST_OFF + (s)*24576;                           \
        const char* Bbuf = Abuf + 16384;                                       \
        bf16x8 af[2];                                                          \
        _Pragma("unroll")                                                      \
        for (int mi = 0; mi < 2; mi++){                                        \
            int row = wr*32 + mi*16 + lr;                                      \
            int aoff = row*128 + ((q*32) ^ ((row & 7) << 4));                  \
            f32x4 a0 = *(const f32x4*)(Abuf + aoff);                           \
            f32x4 a1 = *(const f32x4*)(Abuf + (aoff ^ 16));                    \
            union { u32 w[4]; bf16x8 v; } u;                                   \
            u.w[0] = cvtpk(a0.x, a0.y); u.w[1] = cvtpk(a0.z, a0.w);            \
            u.w[2] = cvtpk(a1.x, a1.y); u.w[3] = cvtpk(a1.z, a1.w);            \
            af[mi] = u.v;                                                      \
        }                                                                      \
        _Pragma("unroll")                                                      \
        for (int ni = 0; ni < 4; ni++){                                        \
            int col = wc*64 + ni*16 + lr;                                      \
            int boff = col*64 + ((q*16) ^ (((col >> 1) & 3) << 4));            \
            bf16x8 bf = *(const bf16x8*)(Bbuf + boff);                         \
            acc[0][ni] = __builtin_amdgcn_mfma_f32_16x16x32_bf16(af[0], bf, acc[0][ni], 0, 0, 0); \
            acc[1][ni] = __builtin_amdgcn_mfma_f32_16x16x32_bf16(af[1], bf, acc[1][ni], 0, 0, 0); \
        }                                                                      \
    }while(0)

    f32x4 acc[2][4];
    #pragma unroll
    for (int i = 0; i < 2; i++)
        #pragma unroll
        for (int j = 0; j < 4; j++) acc[i][j] = {0.f, 0.f, 0.f, 0.f};

    PSTAGE(0, 0);
    int cur = 0;
    #pragma unroll 1
    for (int m = 0; m < 3; m++){
        #pragma unroll 1
        for (int kt = 0; kt < 24; kt++){
            int t = m*24 + kt;
            __builtin_amdgcn_sched_barrier(0);
            __builtin_amdgcn_s_barrier();                  // reads of slot cur^1 done
            if (t < 71){
                PSTAGE(cur ^ 1, t + 1);
                asm volatile("s_waitcnt vmcnt(3)" ::: "memory");   // chunk t landed
            } else {
                asm volatile("s_waitcnt vmcnt(0)" ::: "memory");
            }
            __builtin_amdgcn_s_barrier();
            __builtin_amdgcn_sched_barrier(0);
            PCONSUME(cur);
            cur ^= 1;
        }
        // modality epilogue: x(+bias) -> Xs image (bf16), reset acc
        const float* pbL = (const float*)(lds + GWT_OFF);
        #pragma unroll
        for (int mi = 0; mi < 2; mi++)
            #pragma unroll
            for (int ni = 0; ni < 4; ni++){
                int lcol = wc*64 + ni*16 + lr;
                int colg = m*128 + lcol;
                int ktI = colg >> 5, qI = (colg >> 3) & 3, el = colg & 7;
                float bias = pbL[m*128 + lcol];
                #pragma unroll
                for (int j = 0; j < 4; j++){
                    int row = wr*32 + mi*16 + q*4 + j;
                    *(u16*)(lds + (row >> 6)*49152 + ktI*4096 + qI*1024
                            + (row & 63)*16 + el*2) = f2bf(acc[mi][ni][j] + bias);
                    acc[mi][ni][j] = 0.f;
                }
            }
    }
#undef PSTAGE
#undef PCONSUME
    asm volatile("s_waitcnt lgkmcnt(0)" ::: "memory");
    __builtin_amdgcn_sched_barrier(0);
    __builtin_amdgcn_s_barrier();                          // Xs image complete

    // stage expert chunk 0 into WB slot0 (proj stage region now dead)
    async_cp16(lds + WB_OFF + tid*16, w1b + tid*16);

    // ---- gate: one MFMA column per wave, softmax over 8 lanes ----
    {
        f32x4 ga = {0.f, 0.f, 0.f, 0.f};
        const char* xb = lds + (wid >> 2)*49152 + ((wid & 3)*16 + lr)*16 + q*1024;
        const u16* gwp = gwimg + lr*384 + q*8;
        #pragma unroll
        for (int kt = 0; kt < 12; kt++){
            bf16x8 af = *(const bf16x8*)(xb + kt*4096);
            bf16x8 gb = *(const bf16x8*)(gwp + kt*32);
            ga = __builtin_amdgcn_mfma_f32_16x16x32_bf16(af, gb, ga, 0, 0, 0);
        }
        float gbv = gate_b[lr & 7];
        float gw4[4];
        #pragma unroll
        for (int j = 0; j < 4; j++){
            float v = ga[j] + gbv;
            float mx = v;
            mx = fmaxf(mx, __shfl_xor(mx, 1));
            mx = fmaxf(mx, __shfl_xor(mx, 2));
            mx = fmaxf(mx, __shfl_xor(mx, 4));
            float s = __expf(v - mx);
            float t = s;
            t += __shfl_xor(t, 1);
            t += __shfl_xor(t, 2);
            t += __shfl_xor(t, 4);
            gw4[j] = s / t;
        }
        __builtin_amdgcn_s_barrier();                      // proj_b reads done before GWT overwrite
        if (lr < 8){
            f32x4 wv = {gw4[0], gw4[1], gw4[2], gw4[3]};
            *(f32x4*)(lds + GWT_OFF + lr*512 + (wid*16 + q*4)*4) = wv;
        }
    }
    asm volatile("s_waitcnt vmcnt(0) lgkmcnt(0)" ::: "memory");   // WB0 + GWT landed
    __builtin_amdgcn_sched_barrier(0);
    __builtin_amdgcn_s_barrier();

    // ---- expert pipeline: 128 chunks, dbuf, counted vmcnt ----
    f32x4 fus[2][4];
    #pragma unroll
    for (int i = 0; i < 2; i++)
        #pragma unroll
        for (int j = 0; j < 4; j++) fus[i][j] = {0.f, 0.f, 0.f, 0.f};
    cur = 0;

    #pragma unroll 1
    for (int e = 0; e < 8; e++){
        f32x4 ac1[2][4];
        #pragma unroll
        for (int i = 0; i < 2; i++)
            #pragma unroll
            for (int j = 0; j < 4; j++) ac1[i][j] = {0.f, 0.f, 0.f, 0.f};

        #pragma unroll 1
        for (int ph = 0; ph < 12; ph++){
            __builtin_amdgcn_sched_barrier(0);
            __builtin_amdgcn_s_barrier();
            {   // stage chunk g+1
                int gn = e*16 + ph + 1;
                int en = gn >> 4, pn = gn & 15;
                const char* src = (pn < 12) ? (w1b + en*98304 + pn*8192)
                                            : (w2b + en*32768 + (pn - 12)*8192);
                async_cp16(lds + WB_OFF + (cur ^ 1)*8192 + tid*16, src + tid*16);
            }
            asm volatile("s_waitcnt vmcnt(1)" ::: "memory");
            __builtin_amdgcn_s_barrier();
            __builtin_amdgcn_sched_barrier(0);
            const char* wsl = lds + WB_OFF + cur*8192 + q*2048;
            const char* xa  = lds + (wr >> 1)*49152 + ph*4096 + q*1024;
            bf16x8 af0 = *(const bf16x8*)(xa + ((wr & 1)*32 + lr)*16);
            bf16x8 af1 = *(const bf16x8*)(xa + ((wr & 1)*32 + 16 + lr)*16);
            #pragma unroll
            for (int ni = 0; ni < 4; ni++){
                bf16x8 bf = *(const bf16x8*)(wsl + (wc*64 + ni*16 + lr)*16);
                ac1[0][ni] = __builtin_amdgcn_mfma_f32_16x16x32_bf16(af0, bf, ac1[0][ni], 0, 0, 0);
                ac1[1][ni] = __builtin_amdgcn_mfma_f32_16x16x32_bf16(af1, bf, ac1[1][ni], 0, 0, 0);
            }
            cur ^= 1;
        }
        // h = relu(ac1 + b1) -> Hs
        #pragma unroll
        for (int mi = 0; mi < 2; mi++)
            #pragma unroll
            for (int ni = 0; ni < 4; ni++){
                int col = wc*64 + ni*16 + lr;
                float b1v = bf2f(b1L[e*128 + col]);
                #pragma unroll
                for (int j = 0; j < 4; j++){
                    int row = wr*32 + mi*16 + q*4 + j;
                    Hs[row*136 + col] = f2bf(fmaxf(ac1[mi][ni][j] + b1v, 0.f));
                }
            }
        asm volatile("s_waitcnt lgkmcnt(0)" ::: "memory");
        __builtin_amdgcn_sched_barrier(0);

        f32x4 ac2[2][4];
        #pragma unroll
        for (int i = 0; i < 2; i++)
            #pragma unroll
            for (int j = 0; j < 4; j++) ac2[i][j] = {0.f, 0.f, 0.f, 0.f};

        #pragma unroll 1
        for (int p2 = 0; p2 < 4; p2++){
            __builtin_amdgcn_sched_barrier(0);
            __builtin_amdgcn_s_barrier();
            {   // stage chunk g+1 (clamped dummy at the very end)
                int gn = e*16 + 13 + p2;
                if (gn > 127) gn = 127;
                int en = gn >> 4, pn = gn & 15;
                const char* src = (pn < 12) ? (w1b + en*98304 + pn*8192)
                                            : (w2b + en*32768 + (pn - 12)*8192);
                async_cp16(lds + WB_OFF + (cur ^ 1)*8192 + tid*16, src + tid*16);
            }
            asm volatile("s_waitcnt vmcnt(1)" ::: "memory");
            __builtin_amdgcn_s_barrier();
            __builtin_amdgcn_sched_barrier(0);
            const char* wsl = lds + WB_OFF + cur*8192 + q*2048;
            const char* hb  = (const char*)Hs + (p2*32 + q*8)*2;
            bf16x8 af0 = *(const bf16x8*)(hb + (wr*32 + lr)*272);
            bf16x8 af1 = *(const bf16x8*)(hb + (wr*32 + 16 + lr)*272);
            #pragma unroll
            for (int ni = 0; ni < 4; ni++){
                bf16x8 bf = *(const bf16x8*)(wsl + (wc*64 + ni*16 + lr)*16);
                ac2[0][ni] = __builtin_amdgcn_mfma_f32_16x16x32_bf16(af0, bf, ac2[0][ni], 0, 0, 0);
                ac2[1][ni] = __builtin_amdgcn_mfma_f32_16x16x32_bf16(af1, bf, ac2[1][ni], 0, 0, 0);
            }
            cur ^= 1;
        }
        // fused += gw[:,e] * (eo + b2)
        #pragma unroll
        for (int mi = 0; mi < 2; mi++){
            f32x4 gwv = *(const f32x4*)(lds + GWT_OFF + e*512 + (wr*32 + mi*16 + q*4)*4);
            #pragma unroll
            for (int ni = 0; ni < 4; ni++){
                int col = wc*64 + ni*16 + lr;
                float b2v = bf2f(b2L[e*128 + col]);
                #pragma unroll
                for (int j = 0; j < 4; j++)
                    fus[mi][ni][j] += gwv[j] * (ac2[mi][ni][j] + b2v);
            }
        }
    }

    asm volatile("s_waitcnt vmcnt(0)" ::: "memory");   // drain dummy stage
    __builtin_amdgcn_sched_barrier(0);
    __builtin_amdgcn_s_barrier();                      // all Hs(h7) reads done
    // fused -> Hs (bf16)
    #pragma unroll
    for (int mi = 0; mi < 2; mi++)
        #pragma unroll
        for (int ni = 0; ni < 4; ni++){
            int col = wc*64 + ni*16 + lr;
            #pragma unroll
            for (int j = 0; j < 4; j++){
                int row = wr*32 + mi*16 + q*4 + j;
                Hs[row*136 + col] = f2bf(fus[mi][ni][j]);
            }
        }
    asm volatile("s_waitcnt lgkmcnt(0)" ::: "memory");
    __builtin_amdgcn_sched_barrier(0);
    __builtin_amdgcn_s_barrier();

    // ---- penult = relu(fused @ pre_w + pre_b): wave wid -> rows wid*16..+16 ----
    f32x4 ap[4];
    #pragma unroll
    for (int i = 0; i < 4; i++) ap[i] = {0.f, 0.f, 0.f, 0.f};
    #pragma unroll
    for (int kt = 0; kt < 4; kt++){
        bf16x8 af = *(const bf16x8*)((const char*)Hs + (wid*16 + lr)*272 + (kt*32 + q*8)*2);
        #pragma unroll
        for (int ni = 0; ni < 4; ni++){
            bf16x8 bf = *(const bf16x8*)(prwT + (size_t)(ni*16 + lr)*128 + kt*32 + q*8);
            ap[ni] = __builtin_amdgcn_mfma_f32_16x16x32_bf16(af, bf, ap[ni], 0, 0, 0);
        }
    }
    float* Pen = (float*)lds;   // [128][68], Xs region dead
    #pragma unroll
    for (int ni = 0; ni < 4; ni++){
        int col = ni*16 + lr;
        float pbv = pre_b[col];
        #pragma unroll
        for (int j = 0; j < 4; j++){
            int row = wid*16 + q*4 + j;
            Pen[row*68 + col] = fmaxf(ap[ni][j] + pbv, 0.f);
        }
    }
    asm volatile("s_waitcnt lgkmcnt(0)" ::: "memory");
    __builtin_amdgcn_sched_barrier(0);
    __builtin_amdgcn_s_barrier();
    // ---- head ----
    if (tid < 256){
        int r = tid >> 1, c = tid & 1;
        float s = head_b[c];
        #pragma unroll 8
        for (int k = 0; k < 64; k++) s += Pen[r*68 + k] * head_w[k*2 + c];
        out[(size_t)(blk*128 + r)*2 + c] = s;
    }
}

extern "C" void kernel_launch(void* const* d_in, const int* in_sizes, int n_in,
                              void* d_out, int out_size, void* d_ws, size_t ws_size,
                              hipStream_t stream) {
    const float* ft     = (const float*)d_in[0];
    const float* fa     = (const float*)d_in[1];
    const float* fv     = (const float*)d_in[2];
    const float* proj_w = (const float*)d_in[3];
    const float* proj_b = (const float*)d_in[4];
    const float* exp_w1 = (const float*)d_in[5];
    const float* exp_b1 = (const float*)d_in[6];
    const float* exp_w2 = (const float*)d_in[7];
    const float* exp_b2 = (const float*)d_in[8];
    const float* gate_w = (const float*)d_in[9];
    const float* gate_b = (const float*)d_in[10];
    const float* pre_w  = (const float*)d_in[11];
    const float* pre_b  = (const float*)d_in[12];
    const float* head_w = (const float*)d_in[13];
    const float* head_b = (const float*)d_in[14];
    float* out = (float*)d_out;

    u16* pimg  = (u16*)d_ws;                      // 294912
    u16* w1img = pimg + 294912;                   // 393216
    u16* w2img = w1img + 393216;                  // 131072
    u16* prwT  = w2img + 131072;                  // 8192
    u16* gwimg = prwT + 8192;                     // 6144

    cast_weights_kernel<<<3256, 256, 0, stream>>>(proj_w, exp_w1, exp_w2, pre_w, gate_w,
                                                  pimg, w1img, w2img, prwT, gwimg);
    fused_kernel<<<256, 512, 0, stream>>>(ft, fa, fv, pimg, proj_b,
                                          w1img, w2img, prwT, gwimg,
                                          gate_b, exp_b1, exp_b2,
                                          pre_b, head_w, head_b, out);
}

// Round 10
// 121.010 us; speedup vs baseline: 1.1621x; 1.0128x over previous
//
#include <hip/hip_runtime.h>
#include <hip/hip_bf16.h>

#define B_ROWS 32768

typedef unsigned short u16;
typedef unsigned int u32;
typedef float f32x4 __attribute__((ext_vector_type(4)));
typedef __bf16 bf16x8 __attribute__((ext_vector_type(8)));

__device__ __forceinline__ u16 f2bf(float f){
    union { float f; u32 u; } v; v.f = f;
    return (u16)((v.u + 0x7FFFu + ((v.u >> 16) & 1u)) >> 16);
}
__device__ __forceinline__ float bf2f(u16 h){
    union { u32 u; float f; } v; v.u = ((u32)h) << 16; return v.f;
}
__device__ __forceinline__ u32 cvtpk(float lo, float hi){
    u32 r;
    asm("v_cvt_pk_bf16_f32 %0, %1, %2" : "=v"(r) : "v"(lo), "v"(hi));
    return r;
}
__device__ __forceinline__ void async_cp16(void* lds_dst, const void* g_src){
    __builtin_amdgcn_global_load_lds(
        (const __attribute__((address_space(1))) unsigned int*)g_src,
        (__attribute__((address_space(3))) unsigned int*)lds_dst, 16, 0, 0);
}

// ---------------- weight cast/transpose into staging-friendly images ----------
// pimg : [3][24][4096 u16]  XOR-swizzled proj-B LDS chunk image (BK=32)
// w1img: [8][12 chunks][q:4][col:128][8]
// w2img: [8][4 chunks][q:4][col:128][8]
// prwT : [64][128] plain [o][k]
// gwimg: [16][384] zero-padded gate weights, [e][k]
__global__ void cast_weights_kernel(const float* __restrict__ proj_w,
                                    const float* __restrict__ exp_w1,
                                    const float* __restrict__ exp_w2,
                                    const float* __restrict__ pre_w,
                                    const float* __restrict__ gate_w,
                                    u16* __restrict__ pimg, u16* __restrict__ w1img,
                                    u16* __restrict__ w2img, u16* __restrict__ prwT,
                                    u16* __restrict__ gwimg){
    int i = blockIdx.x * 256 + threadIdx.x;
    if (i < 294912){                       // pimg (BK=32 chunks)
        int m = i / 98304, r = i % 98304;
        int c = r / 4096, rr = r % 4096;
        int col = rr >> 5, kk = rr & 31;
        int kb = kk ^ (((col >> 1) & 3) << 3);
        pimg[i] = f2bf(proj_w[m*98304 + (c*32 + kb)*128 + col]);
    } else if (i < 688128){                // w1img
        int j = i - 294912;
        int e = j / 49152, r = j % 49152;
        int ph = r / 4096, rr = r % 4096;
        int q = rr >> 10, col = (rr >> 3) & 127, el = rr & 7;
        w1img[j] = f2bf(exp_w1[e*49152 + (ph*32 + q*8 + el)*128 + col]);
    } else if (i < 819200){                // w2img
        int j = i - 688128;
        int e = j / 16384, r = j % 16384;
        int c2 = r / 4096, rr = r % 4096;
        int q = rr >> 10, col = (rr >> 3) & 127, el = rr & 7;
        w2img[j] = f2bf(exp_w2[e*16384 + (c2*32 + q*8 + el)*128 + col]);
    } else if (i < 827392){                // prwT
        int j = i - 819200;
        int o = j / 128, k = j % 128;
        prwT[j] = f2bf(pre_w[k*64 + o]);
    } else if (i < 833536){                // gwimg
        int j = i - 827392;
        int e = j / 384, k = j % 384;
        gwimg[j] = (e < 8) ? f2bf(gate_w[k*8 + e]) : (u16)0;
    }
}

// ---------------- fully fused: proj + gate + experts + pre + head -------------
// 256 blocks x 512 threads (8 waves 4x2), 128 rows/block, 1 block/CU, 160KB LDS.
// Phase A: depth-2 pipeline — A feats 3-slot ring (HBM), B pimg 2-slot (L2);
//   steady wait vmcnt(5).
// Phase C: depth-2 — 3-slot WB ring, steady vmcnt(2).
// Hs is XOR-swizzled (stride 256B, byte ^= (row&7)<<4) — saves the 2048B pad,
// which pays for GWT's full 4096B (the r9 overlap bug).
#define XS_OFF   0          // 96 KB  x image [half2][kt12][q4][row64][16B]
#define A_OFF    98304      // 3 x 16 KB A-feat ring (phase A)
#define B_OFF    147456     // 2 x 8 KB pimg ring (phase A)
#define HS_OFF   98304      // phase C: 128 x 256B XOR-swizzled = 32768
#define GWT_OFF  131072     // f32 [8][128] = 4096
#define B1_OFF   135168     // bf16 [8][128] = 2048
#define B2_OFF   137216     // bf16 [8][128] = 2048
#define WB_OFF   139264     // 3 x 8 KB expert ring -> 163840

__global__ __launch_bounds__(512, 2) void fused_kernel(
    const float* __restrict__ ft, const float* __restrict__ fa, const float* __restrict__ fv,
    const u16* __restrict__ pimg, const float* __restrict__ proj_b,
    const u16* __restrict__ w1img, const u16* __restrict__ w2img,
    const u16* __restrict__ prwT, const u16* __restrict__ gwimg,
    const float* __restrict__ gate_b, const float* __restrict__ exp_b1, const float* __restrict__ exp_b2,
    const float* __restrict__ pre_b, const float* __restrict__ head_w, const float* __restrict__ head_b,
    float* __restrict__ out)
{
    __shared__ __align__(16) char lds[163840];
    const int tid = threadIdx.x;
    const int lane = tid & 63, wid = tid >> 6;   // 8 waves
    const int wr = wid >> 1, wc = wid & 1;       // 4 x 2
    const int lr = lane & 15, q = lane >> 4;
    const int blk = blockIdx.x;
    const int row0 = blk * 128;
    const char* w1b = (const char*)w1img;
    const char* w2b = (const char*)w2img;
    char* HsB = lds + HS_OFF;
    u16* b1L = (u16*)(lds + B1_OFF);
    u16* b2L = (u16*)(lds + B2_OFF);

    // ---- prologue: proj_b -> registers (per-lane cols), drain, then pipeline ----
    float pb0[4], pb1[4], pb2[4];
    #pragma unroll
    for (int ni = 0; ni < 4; ni++){
        int c = wc*64 + ni*16 + lr;
        pb0[ni] = proj_b[c];
        pb1[ni] = proj_b[128 + c];
        pb2[ni] = proj_b[256 + c];
    }
    asm volatile("s_waitcnt vmcnt(0)" ::: "memory");

    // A staging source offsets (XOR-pre-swizzled global addresses, linear LDS dst)
    u32 aoffs[2];
    #pragma unroll
    for (int i = 0; i < 2; i++){
        int P = i*8192 + tid*16;
        int row = P >> 7, inner = P & 127;
        aoffs[i] = (u32)((row0 + row)*3072 + (inner ^ ((row & 7) << 4)));
    }

#define ASTAGE(c) do{                                                          \
        int mm_ = (c) / 24, kk_ = (c) % 24;                                    \
        const char* ab_ = (const char*)(mm_ == 0 ? ft : mm_ == 1 ? fa : fv);   \
        char* la_ = lds + A_OFF + ((c) % 3)*16384 + tid*16;                    \
        async_cp16(la_,        ab_ + aoffs[0] + kk_*128);                      \
        async_cp16(la_ + 8192, ab_ + aoffs[1] + kk_*128);                      \
    }while(0)

#define BSTAGE(c) do{                                                          \
        int mm_ = (c) / 24, kk_ = (c) % 24;                                    \
        async_cp16(lds + B_OFF + ((c) % 2)*8192 + tid*16,                      \
                   (const char*)pimg + mm_*196608 + kk_*8192 + tid*16);        \
    }while(0)

#define PCONSUME(c) do{                                                        \
        const char* Abuf = lds + A_OFF + ((c) % 3)*16384;                      \
        const char* Bbuf = lds + B_OFF + ((c) % 2)*8192;                       \
        bf16x8 af[2];                                                          \
        _Pragma("unroll")                                                      \
        for (int mi = 0; mi < 2; mi++){                                        \
            int row = wr*32 + mi*16 + lr;                                      \
            int aoff = row*128 + ((q*32) ^ ((row & 7) << 4));                  \
            f32x4 a0 = *(const f32x4*)(Abuf + aoff);                           \
            f32x4 a1 = *(const f32x4*)(Abuf + (aoff ^ 16));                    \
            union { u32 w[4]; bf16x8 v; } u;                                   \
            u.w[0] = cvtpk(a0.x, a0.y); u.w[1] = cvtpk(a0.z, a0.w);            \
            u.w[2] = cvtpk(a1.x, a1.y); u.w[3] = cvtpk(a1.z, a1.w);            \
            af[mi] = u.v;                                                      \
        }                                                                      \
        _Pragma("unroll")                                                      \
        for (int ni = 0; ni < 4; ni++){                                        \
            int col = wc*64 + ni*16 + lr;                                      \
            int boff = col*64 + ((q*16) ^ (((col >> 1) & 3) << 4));            \
            bf16x8 bf = *(const bf16x8*)(Bbuf + boff);                         \
            acc[0][ni] = __builtin_amdgcn_mfma_f32_16x16x32_bf16(af[0], bf, acc[0][ni], 0, 0, 0); \
            acc[1][ni] = __builtin_amdgcn_mfma_f32_16x16x32_bf16(af[1], bf, acc[1][ni], 0, 0, 0); \
        }                                                                      \
    }while(0)

// one modality: 24 chunk iterations + epilogue into Xs image (MC is a literal)
#define PHASE_A_MOD(MC, PB) do{                                                \
        _Pragma("unroll 1")                                                    \
        for (int kt = 0; kt < 24; kt++){                                       \
            int t = MC*24 + kt;                                                \
            __builtin_amdgcn_sched_barrier(0);                                 \
            __builtin_amdgcn_s_barrier();                                      \
            if (t < 71) BSTAGE(t + 1);                                         \
            if (t < 70) ASTAGE(t + 2);                                         \
            if (t < 70)       asm volatile("s_waitcnt vmcnt(5)" ::: "memory"); \
            else if (t == 70) asm volatile("s_waitcnt vmcnt(3)" ::: "memory"); \
            else              asm volatile("s_waitcnt vmcnt(0)" ::: "memory"); \
            __builtin_amdgcn_s_barrier();                                      \
            __builtin_amdgcn_sched_barrier(0);                                 \
            PCONSUME(t);                                                       \
        }                                                                      \
        _Pragma("unroll")                                                      \
        for (int mi = 0; mi < 2; mi++)                                         \
            _Pragma("unroll")                                                  \
            for (int ni = 0; ni < 4; ni++){                                    \
                int lcol = wc*64 + ni*16 + lr;                                 \
                int colg = MC*128 + lcol;                                      \
                int ktI = colg >> 5, qI = (colg >> 3) & 3, el = colg & 7;      \
                _Pragma("unroll")                                              \
                for (int j = 0; j < 4; j++){                                   \
                    int row = wr*32 + mi*16 + q*4 + j;                         \
                    *(u16*)(lds + (row >> 6)*49152 + ktI*4096 + qI*1024        \
                            + (row & 63)*16 + el*2) = f2bf(acc[mi][ni][j] + PB[ni]); \
                    acc[mi][ni][j] = 0.f;                                      \
                }                                                              \
            }                                                                  \
    }while(0)

    f32x4 acc[2][4];
    #pragma unroll
    for (int i = 0; i < 2; i++)
        #pragma unroll
        for (int j = 0; j < 4; j++) acc[i][j] = {0.f, 0.f, 0.f, 0.f};

    BSTAGE(0); ASTAGE(0); ASTAGE(1);
    PHASE_A_MOD(0, pb0);
    PHASE_A_MOD(1, pb1);
    PHASE_A_MOD(2, pb2);
#undef ASTAGE
#undef BSTAGE
#undef PCONSUME
#undef PHASE_A_MOD

    asm volatile("s_waitcnt lgkmcnt(0)" ::: "memory");
    __builtin_amdgcn_sched_barrier(0);
    __builtin_amdgcn_s_barrier();                          // Xs image complete

    // ---- phase B: expert chunk 0,1 prefetch; bias stage; gate ----
    async_cp16(lds + WB_OFF + 0*8192 + tid*16, w1b + tid*16);          // c0
    async_cp16(lds + WB_OFF + 1*8192 + tid*16, w1b + 8192 + tid*16);   // c1
    for (int i = tid; i < 1024; i += 512){
        b1L[i] = f2bf(exp_b1[i]);
        b2L[i] = f2bf(exp_b2[i]);
    }
    {
        f32x4 ga = {0.f, 0.f, 0.f, 0.f};
        const char* xb = lds + (wid >> 2)*49152 + ((wid & 3)*16 + lr)*16 + q*1024;
        const u16* gwp = gwimg + lr*384 + q*8;
        #pragma unroll
        for (int kt = 0; kt < 12; kt++){
            bf16x8 af = *(const bf16x8*)(xb + kt*4096);
            bf16x8 gb = *(const bf16x8*)(gwp + kt*32);
            ga = __builtin_amdgcn_mfma_f32_16x16x32_bf16(af, gb, ga, 0, 0, 0);
        }
        float gbv = gate_b[lr & 7];
        float gw4[4];
        #pragma unroll
        for (int j = 0; j < 4; j++){
            float v = ga[j] + gbv;
            float mx = v;
            mx = fmaxf(mx, __shfl_xor(mx, 1));
            mx = fmaxf(mx, __shfl_xor(mx, 2));
            mx = fmaxf(mx, __shfl_xor(mx, 4));
            float s = __expf(v - mx);
            float t = s;
            t += __shfl_xor(t, 1);
            t += __shfl_xor(t, 2);
            t += __shfl_xor(t, 4);
            gw4[j] = s / t;
        }
        if (lr < 8){
            f32x4 wv = {gw4[0], gw4[1], gw4[2], gw4[3]};
            *(f32x4*)(lds + GWT_OFF + lr*512 + (wid*16 + q*4)*4) = wv;
        }
    }
    asm volatile("s_waitcnt vmcnt(0) lgkmcnt(0)" ::: "memory");   // c0,c1,biases,GWT landed
    __builtin_amdgcn_sched_barrier(0);
    __builtin_amdgcn_s_barrier();

    // ---- phase C: expert pipeline, 128 chunks, 3-slot ring, vmcnt(2) ----
#define WSTAGE(g) do{                                                          \
        int gn_ = (g) > 127 ? 127 : (g);                                       \
        int en_ = gn_ >> 4, pn_ = gn_ & 15;                                    \
        const char* src_ = (pn_ < 12) ? (w1b + en_*98304 + pn_*8192)           \
                                      : (w2b + en_*32768 + (pn_ - 12)*8192);   \
        async_cp16(lds + WB_OFF + ((g) % 3)*8192 + tid*16, src_ + tid*16);     \
    }while(0)

    f32x4 fus[2][4];
    #pragma unroll
    for (int i = 0; i < 2; i++)
        #pragma unroll
        for (int j = 0; j < 4; j++) fus[i][j] = {0.f, 0.f, 0.f, 0.f};

    #pragma unroll 1
    for (int e = 0; e < 8; e++){
        f32x4 ac1[2][4];
        #pragma unroll
        for (int i = 0; i < 2; i++)
            #pragma unroll
            for (int j = 0; j < 4; j++) ac1[i][j] = {0.f, 0.f, 0.f, 0.f};

        #pragma unroll 1
        for (int ph = 0; ph < 12; ph++){
            int g = e*16 + ph;
            __builtin_amdgcn_sched_barrier(0);
            __builtin_amdgcn_s_barrier();
            WSTAGE(g + 2);
            asm volatile("s_waitcnt vmcnt(2)" ::: "memory");
            __builtin_amdgcn_s_barrier();
            __builtin_amdgcn_sched_barrier(0);
            const char* wsl = lds + WB_OFF + (g % 3)*8192 + q*2048;
            const char* xa  = lds + (wr >> 1)*49152 + ph*4096 + q*1024;
            bf16x8 af0 = *(const bf16x8*)(xa + ((wr & 1)*32 + lr)*16);
            bf16x8 af1 = *(const bf16x8*)(xa + ((wr & 1)*32 + 16 + lr)*16);
            #pragma unroll
            for (int ni = 0; ni < 4; ni++){
                bf16x8 bf = *(const bf16x8*)(wsl + (wc*64 + ni*16 + lr)*16);
                ac1[0][ni] = __builtin_amdgcn_mfma_f32_16x16x32_bf16(af0, bf, ac1[0][ni], 0, 0, 0);
                ac1[1][ni] = __builtin_amdgcn_mfma_f32_16x16x32_bf16(af1, bf, ac1[1][ni], 0, 0, 0);
            }
        }
        // h = relu(ac1 + b1) -> Hs (XOR-swizzled)
        #pragma unroll
        for (int mi = 0; mi < 2; mi++)
            #pragma unroll
            for (int ni = 0; ni < 4; ni++){
                int col = wc*64 + ni*16 + lr;
                float b1v = bf2f(b1L[e*128 + col]);
                #pragma unroll
                for (int j = 0; j < 4; j++){
                    int row = wr*32 + mi*16 + q*4 + j;
                    *(u16*)(HsB + row*256 + ((col*2) ^ ((row & 7) << 4)))
                        = f2bf(fmaxf(ac1[mi][ni][j] + b1v, 0.f));
                }
            }
        asm volatile("s_waitcnt lgkmcnt(0)" ::: "memory");
        __builtin_amdgcn_sched_barrier(0);

        f32x4 ac2[2][4];
        #pragma unroll
        for (int i = 0; i < 2; i++)
            #pragma unroll
            for (int j = 0; j < 4; j++) ac2[i][j] = {0.f, 0.f, 0.f, 0.f};

        #pragma unroll 1
        for (int p2 = 0; p2 < 4; p2++){
            int g = e*16 + 12 + p2;
            __builtin_amdgcn_sched_barrier(0);
            __builtin_amdgcn_s_barrier();
            WSTAGE(g + 2);
            asm volatile("s_waitcnt vmcnt(2)" ::: "memory");
            __builtin_amdgcn_s_barrier();
            __builtin_amdgcn_sched_barrier(0);
            const char* wsl = lds + WB_OFF + (g % 3)*8192 + q*2048;
            int cb = p2*64 + q*16;
            int rowA = wr*32 + lr;
            int rowB = wr*32 + 16 + lr;
            bf16x8 af0 = *(const bf16x8*)(HsB + rowA*256 + (cb ^ ((rowA & 7) << 4)));
            bf16x8 af1 = *(const bf16x8*)(HsB + rowB*256 + (cb ^ ((rowB & 7) << 4)));
            #pragma unroll
            for (int ni = 0; ni < 4; ni++){
                bf16x8 bf = *(const bf16x8*)(wsl + (wc*64 + ni*16 + lr)*16);
                ac2[0][ni] = __builtin_amdgcn_mfma_f32_16x16x32_bf16(af0, bf, ac2[0][ni], 0, 0, 0);
                ac2[1][ni] = __builtin_amdgcn_mfma_f32_16x16x32_bf16(af1, bf, ac2[1][ni], 0, 0, 0);
            }
        }
        // fused += gw[:,e] * (eo + b2)
        #pragma unroll
        for (int mi = 0; mi < 2; mi++){
            f32x4 gwv = *(const f32x4*)(lds + GWT_OFF + e*512 + (wr*32 + mi*16 + q*4)*4);
            #pragma unroll
            for (int ni = 0; ni < 4; ni++){
                int col = wc*64 + ni*16 + lr;
                float b2v = bf2f(b2L[e*128 + col]);
                #pragma unroll
                for (int j = 0; j < 4; j++)
                    fus[mi][ni][j] += gwv[j] * (ac2[mi][ni][j] + b2v);
            }
        }
    }
#undef WSTAGE

    asm volatile("s_waitcnt vmcnt(0)" ::: "memory");   // drain dummy stages
    __builtin_amdgcn_sched_barrier(0);
    __builtin_amdgcn_s_barrier();                      // all Hs(h7) reads done
    // fused -> Hs (bf16, XOR-swizzled)
    #pragma unroll
    for (int mi = 0; mi < 2; mi++)
        #pragma unroll
        for (int ni = 0; ni < 4; ni++){
            int col = wc*64 + ni*16 + lr;
            #pragma unroll
            for (int j = 0; j < 4; j++){
                int row = wr*32 + mi*16 + q*4 + j;
                *(u16*)(HsB + row*256 + ((col*2) ^ ((row & 7) << 4))) = f2bf(fus[mi][ni][j]);
            }
        }
    asm volatile("s_waitcnt lgkmcnt(0)" ::: "memory");
    __builtin_amdgcn_sched_barrier(0);
    __builtin_amdgcn_s_barrier();

    // ---- penult = relu(fused @ pre_w + pre_b): wave wid -> rows wid*16..+16 ----
    f32x4 ap[4];
    #pragma unroll
    for (int i = 0; i < 4; i++) ap[i] = {0.f, 0.f, 0.f, 0.f};
    #pragma unroll
    for (int kt = 0; kt < 4; kt++){
        int row = wid*16 + lr;
        int cb = kt*64 + q*16;
        bf16x8 af = *(const bf16x8*)(HsB + row*256 + (cb ^ ((row & 7) << 4)));
        #pragma unroll
        for (int ni = 0; ni < 4; ni++){
            bf16x8 bf = *(const bf16x8*)(prwT + (size_t)(ni*16 + lr)*128 + kt*32 + q*8);
            ap[ni] = __builtin_amdgcn_mfma_f32_16x16x32_bf16(af, bf, ap[ni], 0, 0, 0);
        }
    }
    float* Pen = (float*)lds;   // [128][68], Xs region dead
    #pragma unroll
    for (int ni = 0; ni < 4; ni++){
        int col = ni*16 + lr;
        float pbv = pre_b[col];
        #pragma unroll
        for (int j = 0; j < 4; j++){
            int row = wid*16 + q*4 + j;
            Pen[row*68 + col] = fmaxf(ap[ni][j] + pbv, 0.f);
        }
    }
    asm volatile("s_waitcnt lgkmcnt(0)" ::: "memory");
    __builtin_amdgcn_sched_barrier(0);
    __builtin_amdgcn_s_barrier();
    // ---- head ----
    if (tid < 256){
        int r = tid >> 1, c = tid & 1;
        float s = head_b[c];
        #pragma unroll 8
        for (int k = 0; k < 64; k++) s += Pen[r*68 + k] * head_w[k*2 + c];
        out[(size_t)(blk*128 + r)*2 + c] = s;
    }
}

extern "C" void kernel_launch(void* const* d_in, const int* in_sizes, int n_in,
                              void* d_out, int out_size, void* d_ws, size_t ws_size,
                              hipStream_t stream) {
    const float* ft     = (const float*)d_in[0];
    const float* fa     = (const float*)d_in[1];
    const float* fv     = (const float*)d_in[2];
    const float* proj_w = (const float*)d_in[3];
    const float* proj_b = (const float*)d_in[4];
    const float* exp_w1 = (const float*)d_in[5];
    const float* exp_b1 = (const float*)d_in[6];
    const float* exp_w2 = (const float*)d_in[7];
    const float* exp_b2 = (const float*)d_in[8];
    const float* gate_w = (const float*)d_in[9];
    const float* gate_b = (const float*)d_in[10];
    const float* pre_w  = (const float*)d_in[11];
    const float* pre_b  = (const float*)d_in[12];
    const float* head_w = (const float*)d_in[13];
    const float* head_b = (const float*)d_in[14];
    float* out = (float*)d_out;

    u16* pimg  = (u16*)d_ws;                      // 294912
    u16* w1img = pimg + 294912;                   // 393216
    u16* w2img = w1img + 393216;                  // 131072
    u16* prwT  = w2img + 131072;                  // 8192
    u16* gwimg = prwT + 8192;                     // 6144

    cast_weights_kernel<<<3256, 256, 0, stream>>>(proj_w, exp_w1, exp_w2, pre_w, gate_w,
                                                  pimg, w1img, w2img, prwT, gwimg);
    fused_kernel<<<256, 512, 0, stream>>>(ft, fa, fv, pimg, proj_b,
                                          w1img, w2img, prwT, gwimg,
                                          gate_b, exp_b1, exp_b2,
                                          pre_b, head_w, head_b, out);
}